// Round 1
// baseline (4448.990 us; speedup 1.0000x reference)
//
#include <hip/hip_runtime.h>
#include <math.h>

#define NDIM 64

__device__ __forceinline__ float wave_sum(float v) {
    #pragma unroll
    for (int off = 1; off < 64; off <<= 1) v += __shfl_xor(v, off, 64);
    return v;
}
__device__ __forceinline__ float wave_min(float v) {
    #pragma unroll
    for (int off = 1; off < 64; off <<= 1) v = fminf(v, __shfl_xor(v, off, 64));
    return v;
}
__device__ __forceinline__ float wave_max(float v) {
    #pragma unroll
    for (int off = 1; off < 64; off <<= 1) v = fmaxf(v, __shfl_xor(v, off, 64));
    return v;
}

// One 64-thread wave per batch element. Thread t owns row t of the
// symmetrized matrix in registers. Householder tridiagonalization
// (eigenvalues only) followed by 64-way Sturm multisection for the
// idx-th eigenvalue (ascending).
__global__ __launch_bounds__(64)
void bispec_eig_kernel(const float* __restrict__ x, const float* __restrict__ y,
                       const float* __restrict__ A, const float* __restrict__ B,
                       const float* __restrict__ C, const int* __restrict__ idxp,
                       float* __restrict__ out, int batch) {
    const int b = blockIdx.x;
    const int t = threadIdx.x;
    if (b >= batch) return;

    __shared__ float xs[NDIM], ys[NDIM];
    __shared__ float vw[2 * NDIM];   // interleaved v, w
    __shared__ float esh[NDIM];
    __shared__ float dsh[NDIM];
    __shared__ float e2sh[NDIM];

    const float xi = x[b * NDIM + t];
    const float yi = y[b * NDIM + t];
    xs[t] = xi;
    ys[t] = yi;
    __syncthreads();

    // Build symmetrized row t: r[j] = 0.5*(M[t][j] + M[j][t]),
    // M[i][j] = A[i][j] + B[i][j]*x[j] + C[i][j]*y[j]   (JAX eigh symmetrize)
    float r[NDIM];
    #pragma unroll
    for (int j = 0; j < NDIM; ++j) {
        float mtj = A[t * NDIM + j] + B[t * NDIM + j] * xs[j] + C[t * NDIM + j] * ys[j];
        float mjt = A[j * NDIM + t] + B[j * NDIM + t] * xi   + C[j * NDIM + t] * yi;
        r[j] = 0.5f * (mtj + mjt);
    }

    // ---- Householder tridiagonalization (eigenvalues only) ----
    // colreg = current column k entry for this row: Am[t][k]
    float colreg = r[0];
    for (int k = 0; k < NDIM - 2; ++k) {
        float akt = (t > k) ? colreg : 0.0f;        // below-diagonal part of col k
        float s2 = wave_sum(akt * akt);
        float a1 = __shfl(akt, k + 1, 64);
        float sigma = sqrtf(s2);
        float alpha = (a1 >= 0.0f) ? -sigma : sigma;
        if (t == 0) esh[k] = alpha;                 // subdiagonal entry
        float v = akt - ((t == k + 1) ? alpha : 0.0f);
        float vtv = s2 - 2.0f * alpha * a1 + alpha * alpha;   // = 2*sigma*(sigma+|a1|), no cancellation
        float beta = (vtv > 1e-30f) ? 2.0f / vtv : 0.0f;
        vw[2 * t] = v;                              // v==0 for t<=k by construction
        __syncthreads();

        // u = A * v (full row dot; v_j = 0 for j<=k so stale region is inert)
        float u = 0.0f;
        #pragma unroll
        for (int j = 0; j < NDIM; ++j) u = fmaf(r[j], vw[2 * j], u);
        float vtu = wave_sum(v * u);
        float w = (t > k) ? fmaf(-0.5f * beta * beta * vtu, v, beta * u) : 0.0f;
        vw[2 * t + 1] = w;
        __syncthreads();

        // rank-2 update: A -= v w^T + w v^T ; capture next column (k+1)
        float nextcol = colreg;
        #pragma unroll
        for (int j = 0; j < NDIM; ++j) {
            float vj = vw[2 * j];
            float wj = vw[2 * j + 1];
            r[j] -= v * wj + w * vj;
            if (j == k + 1) nextcol = r[j];
        }
        colreg = nextcol;
        __syncthreads();
    }

    // Extract diagonal (runtime index -> unrolled select) and last subdiagonal
    float dval = 0.0f;
    #pragma unroll
    for (int j = 0; j < NDIM; ++j)
        if (t == j) dval = r[j];
    dsh[t] = dval;
    if (t == 63) {
        esh[62] = r[62];
        esh[63] = 0.0f;
    }
    __syncthreads();
    float et = esh[t];
    e2sh[t] = et * et;
    float eprev = (t > 0) ? esh[t - 1] : 0.0f;
    __syncthreads();

    // Gershgorin bounds
    float rad = fabsf(et) + fabsf(eprev);
    float lo = wave_min(dval - rad);
    float hi = wave_max(dval + rad);
    float pad = 1e-3f + 1e-5f * fmaxf(fabsf(lo), fabsf(hi));
    lo -= pad;
    hi += pad;

    int idx = idxp[0];
    idx = idx < 0 ? 0 : (idx > NDIM - 1 ? NDIM - 1 : idx);

    // 64-way multisection: width shrinks 65x per iteration
    for (int it = 0; it < 7; ++it) {
        float wdt = (hi - lo) * (1.0f / 65.0f);
        float s = lo + wdt * (float)(t + 1);
        // Sturm count: # eigenvalues < s
        float q = dsh[0] - s;
        if (fabsf(q) < 1e-20f) q = -1e-20f;
        int cnt = (q < 0.0f) ? 1 : 0;
        for (int i = 1; i < NDIM; ++i) {
            q = dsh[i] - s - e2sh[i - 1] / q;
            if (fabsf(q) < 1e-20f) q = -1e-20f;
            cnt += (q < 0.0f) ? 1 : 0;
        }
        unsigned long long m = __ballot(cnt <= idx);
        int p = (int)__popcll(m);
        float nlo = lo + wdt * (float)p;        // p==0 -> lo unchanged
        float nhi = lo + wdt * (float)(p + 1);  // p==64 -> ~hi
        lo = nlo;
        hi = (p >= 64) ? hi : nhi;
    }

    if (t == 0) out[b] = 0.5f * (lo + hi);
}

extern "C" void kernel_launch(void* const* d_in, const int* in_sizes, int n_in,
                              void* d_out, int out_size, void* d_ws, size_t ws_size,
                              hipStream_t stream) {
    const float* x = (const float*)d_in[0];
    const float* y = (const float*)d_in[1];
    const float* A = (const float*)d_in[2];
    const float* B = (const float*)d_in[3];
    const float* C = (const float*)d_in[4];
    const int* idxp = (const int*)d_in[5];
    float* out = (float*)d_out;
    int batch = in_sizes[0] / NDIM;

    dim3 grid(batch), block(NDIM);
    hipLaunchKernelGGL(bispec_eig_kernel, grid, block, 0, stream,
                       x, y, A, B, C, idxp, out, batch);
}

// Round 2
// 4370.265 us; speedup vs baseline: 1.0180x; 1.0180x over previous
//
#include <hip/hip_runtime.h>
#include <math.h>

#define NDIM 64

__device__ __forceinline__ float wave_sum(float v) {
    #pragma unroll
    for (int off = 1; off < 64; off <<= 1) v += __shfl_xor(v, off, 64);
    return v;
}
__device__ __forceinline__ float wave_min(float v) {
    #pragma unroll
    for (int off = 1; off < 64; off <<= 1) v = fminf(v, __shfl_xor(v, off, 64));
    return v;
}
__device__ __forceinline__ float wave_max(float v) {
    #pragma unroll
    for (int off = 1; off < 64; off <<= 1) v = fmaxf(v, __shfl_xor(v, off, 64));
    return v;
}

// One chunk of Householder iterations k in [K0, K1). Inner loops start at
// compile-time K0+1 (columns <= K0 are inert: v_j = w_j = 0 there), keeping
// r[] statically indexed while skipping dead work.
template<int K0, int K1>
__device__ __forceinline__ float tri_chunk(float (&r)[NDIM], float colreg, const int t,
                                           float* __restrict__ vw,
                                           float* __restrict__ esh,
                                           float* __restrict__ dsh) {
    #pragma unroll 1
    for (int k = K0; k < K1; ++k) {
        float akt = (t > k) ? colreg : 0.0f;        // below-diagonal part of col k
        float s2 = wave_sum(akt * akt);
        float a1 = __shfl(akt, k + 1, 64);
        float sigma = sqrtf(s2);
        float alpha = (a1 >= 0.0f) ? -sigma : sigma;
        if (t == 0) esh[k] = alpha;                 // subdiagonal e[k]
        float v = akt - ((t == k + 1) ? alpha : 0.0f);
        float vtv = s2 - 2.0f * alpha * a1 + alpha * alpha;  // 2*sigma*(sigma+|a1|)
        float beta = (vtv > 1e-30f) ? 2.0f * __builtin_amdgcn_rcpf(vtv) : 0.0f;
        vw[2 * t] = v;                              // v==0 for t<=k
        __syncthreads();

        // u = A*v over active columns only
        float u = 0.0f;
        #pragma unroll
        for (int j = K0 + 1; j < NDIM; ++j) u = fmaf(r[j], vw[2 * j], u);
        float vtu = wave_sum(v * u);
        float w = (t > k) ? fmaf(-0.5f * beta * beta * vtu, v, beta * u) : 0.0f;
        vw[2 * t + 1] = w;
        __syncthreads();

        // rank-2 update over active columns; capture next column k+1
        float nextcol = colreg;
        #pragma unroll
        for (int j = K0 + 1; j < NDIM; ++j) {
            r[j] -= v * vw[2 * j + 1] + w * vw[2 * j];
            if (j == k + 1) nextcol = r[j];
        }
        // row k+1 is final after this iteration; nextcol on thread k+1 is d[k+1]
        if (t == k + 1) dsh[t] = nextcol;
        colreg = nextcol;
        __syncthreads();
    }
    return colreg;
}

__global__ __launch_bounds__(64, 4)
void bispec_eig_kernel(const float* __restrict__ x, const float* __restrict__ y,
                       const float* __restrict__ A, const float* __restrict__ B,
                       const float* __restrict__ C, const int* __restrict__ idxp,
                       float* __restrict__ out, int batch) {
    const int b = blockIdx.x;
    const int t = threadIdx.x;
    if (b >= batch) return;

    __shared__ float xs[NDIM], ys[NDIM];
    __shared__ float vw[2 * NDIM];   // interleaved v, w (b64 broadcast reads)
    __shared__ float esh[NDIM];
    __shared__ float dsh[NDIM];
    __shared__ float e2sh[NDIM];

    const float xi = x[b * NDIM + t];
    const float yi = y[b * NDIM + t];
    xs[t] = xi;
    ys[t] = yi;
    __syncthreads();

    // Symmetrized row t: r[j] = 0.5*(M[t][j] + M[j][t]),
    // M[i][j] = A[i][j] + B[i][j]*x[j] + C[i][j]*y[j]
    float r[NDIM];
    #pragma unroll
    for (int j = 0; j < NDIM; ++j) {
        float mtj = A[t * NDIM + j] + B[t * NDIM + j] * xs[j] + C[t * NDIM + j] * ys[j];
        float mjt = A[j * NDIM + t] + B[j * NDIM + t] * xi   + C[j * NDIM + t] * yi;
        r[j] = 0.5f * (mtj + mjt);
    }

    // ---- Householder tridiagonalization, chunked ----
    float colreg = r[0];
    if (t == 0) dsh[0] = r[0];      // row 0 is never touched
    colreg = tri_chunk< 0, 16>(r, colreg, t, vw, esh, dsh);
    colreg = tri_chunk<16, 32>(r, colreg, t, vw, esh, dsh);
    colreg = tri_chunk<32, 48>(r, colreg, t, vw, esh, dsh);
    colreg = tri_chunk<48, 62>(r, colreg, t, vw, esh, dsh);

    if (t == 63) {
        dsh[63] = r[63];
        esh[62] = r[62];
        esh[63] = 0.0f;
    }
    __syncthreads();

    float dval = dsh[t];
    float et = esh[t];
    e2sh[t] = et * et;
    float eprev = (t > 0) ? esh[t - 1] : 0.0f;
    __syncthreads();

    // Gershgorin bounds
    float rad = fabsf(et) + fabsf(eprev);
    float lo = wave_min(dval - rad);
    float hi = wave_max(dval + rad);
    float pad = 1e-3f + 1e-5f * fmaxf(fabsf(lo), fabsf(hi));
    lo -= pad;
    hi += pad;

    int idx = idxp[0];
    idx = idx < 0 ? 0 : (idx > NDIM - 1 ? NDIM - 1 : idx);

    // 64-way multisection: width shrinks 65x per iteration; 4 iters -> ~1e-5 rel
    #pragma unroll 1
    for (int it = 0; it < 4; ++it) {
        float wdt = (hi - lo) * (1.0f / 65.0f);
        float s = lo + wdt * (float)(t + 1);
        float q = dsh[0] - s;
        q = (fabsf(q) < 1e-12f) ? -1e-12f : q;
        int cnt = (q < 0.0f) ? 1 : 0;
        #pragma unroll
        for (int i = 1; i < NDIM; ++i) {
            q = dsh[i] - s - e2sh[i - 1] * __builtin_amdgcn_rcpf(q);
            q = (fabsf(q) < 1e-12f) ? -1e-12f : q;
            cnt += (q < 0.0f) ? 1 : 0;
        }
        unsigned long long m = __ballot(cnt <= idx);
        int p = (int)__popcll(m);
        float nlo = lo + wdt * (float)p;
        float nhi = lo + wdt * (float)(p + 1);
        lo = nlo;
        hi = (p >= 64) ? hi : nhi;
    }

    if (t == 0) out[b] = 0.5f * (lo + hi);
}

extern "C" void kernel_launch(void* const* d_in, const int* in_sizes, int n_in,
                              void* d_out, int out_size, void* d_ws, size_t ws_size,
                              hipStream_t stream) {
    const float* x = (const float*)d_in[0];
    const float* y = (const float*)d_in[1];
    const float* A = (const float*)d_in[2];
    const float* B = (const float*)d_in[3];
    const float* C = (const float*)d_in[4];
    const int* idxp = (const int*)d_in[5];
    float* out = (float*)d_out;
    int batch = in_sizes[0] / NDIM;

    dim3 grid(batch), block(NDIM);
    hipLaunchKernelGGL(bispec_eig_kernel, grid, block, 0, stream,
                       x, y, A, B, C, idxp, out, batch);
}

// Round 3
// 2740.910 us; speedup vs baseline: 1.6232x; 1.5945x over previous
//
#include <hip/hip_runtime.h>
#include <math.h>

#define NDIM 64

__device__ __forceinline__ float wave_sum(float v) {
    #pragma unroll
    for (int off = 1; off < 64; off <<= 1) v += __shfl_xor(v, off, 64);
    return v;
}
__device__ __forceinline__ float wave_min(float v) {
    #pragma unroll
    for (int off = 1; off < 64; off <<= 1) v = fminf(v, __shfl_xor(v, off, 64));
    return v;
}
__device__ __forceinline__ float wave_max(float v) {
    #pragma unroll
    for (int off = 1; off < 64; off <<= 1) v = fmaxf(v, __shfl_xor(v, off, 64));
    return v;
}

// Householder iterations k in [K0, K1). Columns <= K0 are inert (v_j = w_j = 0),
// so inner loops run j in [K0+1, 64) with static indexing. The next-column
// capture (j == k+1) only needs the compile-time window [K0+1, K1].
template<int K0, int K1>
__device__ __forceinline__ float tri_chunk(float (&r)[NDIM], float colreg, const int t,
                                           float* __restrict__ vw,
                                           float* __restrict__ esh,
                                           float* __restrict__ dsh) {
    #pragma unroll 1
    for (int k = K0; k < K1; ++k) {
        float akt = (t > k) ? colreg : 0.0f;        // below-diagonal part of col k
        float s2 = wave_sum(akt * akt);
        float a1 = __shfl(akt, k + 1, 64);
        float sigma = sqrtf(s2);
        float alpha = (a1 >= 0.0f) ? -sigma : sigma;
        if (t == 0) esh[k] = alpha;                 // subdiagonal e[k]
        float v = akt - ((t == k + 1) ? alpha : 0.0f);
        float vtv = s2 - 2.0f * alpha * a1 + alpha * alpha;  // 2*sigma*(sigma+|a1|)
        float beta = (vtv > 1e-30f) ? 2.0f * __builtin_amdgcn_rcpf(vtv) : 0.0f;
        vw[2 * t] = v;                              // v==0 for t<=k
        __syncthreads();

        // u = A*v over active columns only
        float u = 0.0f;
        #pragma unroll
        for (int j = K0 + 1; j < NDIM; ++j) u = fmaf(r[j], vw[2 * j], u);
        float vtu = wave_sum(v * u);
        float w = (t > k) ? fmaf(-0.5f * beta * beta * vtu, v, beta * u) : 0.0f;
        vw[2 * t + 1] = w;
        __syncthreads();

        // rank-2 update over active columns; capture next column (k+1) only
        // inside the compile-time window where it can live.
        float nextcol = colreg;
        #pragma unroll
        for (int j = K0 + 1; j < NDIM; ++j) {
            r[j] -= v * vw[2 * j + 1] + w * vw[2 * j];
            if (j >= K0 + 1 && j <= K1) {
                if (j == k + 1) nextcol = r[j];
            }
        }
        // row k+1 is final after this iteration; on thread k+1 it is d[k+1]
        if (t == k + 1) dsh[t] = nextcol;
        colreg = nextcol;
        __syncthreads();
    }
    return colreg;
}

__global__ __launch_bounds__(64, 3)
void bispec_eig_kernel(const float* __restrict__ x, const float* __restrict__ y,
                       const float* __restrict__ A, const float* __restrict__ B,
                       const float* __restrict__ C, const int* __restrict__ idxp,
                       float* __restrict__ out, int batch) {
    const int b = blockIdx.x;
    const int t = threadIdx.x;
    if (b >= batch) return;

    __shared__ float xs[NDIM], ys[NDIM];
    __shared__ float vw[2 * NDIM];   // interleaved v, w
    __shared__ float esh[NDIM];
    __shared__ float dsh[NDIM];
    __shared__ float e2sh[NDIM];

    const float xi = x[b * NDIM + t];
    const float yi = y[b * NDIM + t];
    xs[t] = xi;
    ys[t] = yi;
    __syncthreads();

    // Symmetrized row t: r[j] = 0.5*(M[t][j] + M[j][t]),
    // M[i][j] = A[i][j] + B[i][j]*x[j] + C[i][j]*y[j]
    float r[NDIM];
    #pragma unroll
    for (int j = 0; j < NDIM; ++j) {
        float mtj = A[t * NDIM + j] + B[t * NDIM + j] * xs[j] + C[t * NDIM + j] * ys[j];
        float mjt = A[j * NDIM + t] + B[j * NDIM + t] * xi   + C[j * NDIM + t] * yi;
        r[j] = 0.5f * (mtj + mjt);
    }

    // ---- Householder tridiagonalization, 8 chunks of 8 ----
    float colreg = r[0];
    if (t == 0) dsh[0] = r[0];      // row 0 is never modified
    colreg = tri_chunk< 0,  8>(r, colreg, t, vw, esh, dsh);
    colreg = tri_chunk< 8, 16>(r, colreg, t, vw, esh, dsh);
    colreg = tri_chunk<16, 24>(r, colreg, t, vw, esh, dsh);
    colreg = tri_chunk<24, 32>(r, colreg, t, vw, esh, dsh);
    colreg = tri_chunk<32, 40>(r, colreg, t, vw, esh, dsh);
    colreg = tri_chunk<40, 48>(r, colreg, t, vw, esh, dsh);
    colreg = tri_chunk<48, 56>(r, colreg, t, vw, esh, dsh);
    colreg = tri_chunk<56, 62>(r, colreg, t, vw, esh, dsh);

    if (t == 63) {
        dsh[63] = r[63];
        esh[62] = r[62];
        esh[63] = 0.0f;
    }
    __syncthreads();

    float dval = dsh[t];
    float et = esh[t];
    e2sh[t] = et * et;
    float eprev = (t > 0) ? esh[t - 1] : 0.0f;
    __syncthreads();

    // Gershgorin bounds
    float rad = fabsf(et) + fabsf(eprev);
    float lo = wave_min(dval - rad);
    float hi = wave_max(dval + rad);
    float pad = 1e-3f + 1e-5f * fmaxf(fabsf(lo), fabsf(hi));
    lo -= pad;
    hi += pad;

    int idx = idxp[0];
    idx = idx < 0 ? 0 : (idx > NDIM - 1 ? NDIM - 1 : idx);

    // 64-way multisection: width shrinks 65x per iteration; 4 iters ~ 1e-6 rel
    #pragma unroll 1
    for (int it = 0; it < 4; ++it) {
        float wdt = (hi - lo) * (1.0f / 65.0f);
        float s = lo + wdt * (float)(t + 1);
        float q = dsh[0] - s;
        q = (fabsf(q) < 1e-12f) ? -1e-12f : q;
        int cnt = (q < 0.0f) ? 1 : 0;
        #pragma unroll
        for (int i = 1; i < NDIM; ++i) {
            q = dsh[i] - s - e2sh[i - 1] * __builtin_amdgcn_rcpf(q);
            q = (fabsf(q) < 1e-12f) ? -1e-12f : q;
            cnt += (q < 0.0f) ? 1 : 0;
        }
        unsigned long long m = __ballot(cnt <= idx);
        int p = (int)__popcll(m);
        float nlo = lo + wdt * (float)p;
        float nhi = lo + wdt * (float)(p + 1);
        lo = nlo;
        hi = (p >= 64) ? hi : nhi;
    }

    if (t == 0) out[b] = 0.5f * (lo + hi);
}

extern "C" void kernel_launch(void* const* d_in, const int* in_sizes, int n_in,
                              void* d_out, int out_size, void* d_ws, size_t ws_size,
                              hipStream_t stream) {
    const float* x = (const float*)d_in[0];
    const float* y = (const float*)d_in[1];
    const float* A = (const float*)d_in[2];
    const float* B = (const float*)d_in[3];
    const float* C = (const float*)d_in[4];
    const int* idxp = (const int*)d_in[5];
    float* out = (float*)d_out;
    int batch = in_sizes[0] / NDIM;

    dim3 grid(batch), block(NDIM);
    hipLaunchKernelGGL(bispec_eig_kernel, grid, block, 0, stream,
                       x, y, A, B, C, idxp, out, batch);
}

// Round 4
// 1021.654 us; speedup vs baseline: 4.3547x; 2.6828x over previous
//
#include <hip/hip_runtime.h>
#include <math.h>

#define NDIM 64

// Broadcast lane `lane`'s value to all lanes as a wave-uniform (SGPR) float.
// With compile-time `lane` this is a single v_readlane_b32.
__device__ __forceinline__ float rl(float v, int lane) {
    return __uint_as_float((unsigned)__builtin_amdgcn_readlane(__float_as_uint(v), lane));
}

__device__ __forceinline__ float wave_sum(float v) {
    #pragma unroll
    for (int off = 1; off < 64; off <<= 1) v += __shfl_xor(v, off, 64);
    return v;
}
__device__ __forceinline__ float wave_min(float v) {
    #pragma unroll
    for (int off = 1; off < 64; off <<= 1) v = fminf(v, __shfl_xor(v, off, 64));
    return v;
}
__device__ __forceinline__ float wave_max(float v) {
    #pragma unroll
    for (int off = 1; off < 64; off <<= 1) v = fmaxf(v, __shfl_xor(v, off, 64));
    return v;
}

// Householder iterations k in [K0, K1). Columns <= K0 are inert (v_j = w_j = 0),
// so inner loops run j in [K0+1, 64) with static indexing. All cross-lane
// traffic is register-resident via readlane broadcasts — no LDS, no barriers.
template<int K0, int K1>
__device__ __forceinline__ void tri_chunk(float (&r)[NDIM], float& colreg,
                                          float& dval, float& e2val, const int t) {
    #pragma unroll 1
    for (int k = K0; k < K1; ++k) {
        float akt = (t > k) ? colreg : 0.0f;          // below-diagonal part of col k
        float s2 = wave_sum(akt * akt);
        float a1 = rl(akt, k + 1);                    // A[k+1][k] (uniform SGPR lane idx)
        float sigma = sqrtf(s2);
        float alpha = (a1 >= 0.0f) ? -sigma : sigma;  // e[k] = alpha
        e2val = (t == k) ? alpha * alpha : e2val;     // keep e[k]^2 on lane k
        float v = akt - ((t == k + 1) ? alpha : 0.0f);
        float vtv = s2 - 2.0f * alpha * a1 + alpha * alpha;   // 2*sigma*(sigma+|a1|)
        float beta = (vtv > 1e-30f) ? 2.0f * __builtin_amdgcn_rcpf(vtv) : 0.0f;

        // u = A*v over active columns, 4-way accumulator ILP
        float u0 = 0.0f, u1 = 0.0f, u2 = 0.0f, u3 = 0.0f;
        #pragma unroll
        for (int j = K0 + 1; j < NDIM; ++j) {
            float vj = rl(v, j);
            if ((j & 3) == 0)      u0 = fmaf(r[j], vj, u0);
            else if ((j & 3) == 1) u1 = fmaf(r[j], vj, u1);
            else if ((j & 3) == 2) u2 = fmaf(r[j], vj, u2);
            else                   u3 = fmaf(r[j], vj, u3);
        }
        float u = (u0 + u1) + (u2 + u3);
        float vtu = wave_sum(v * u);
        float w = (t > k) ? fmaf(-0.5f * beta * beta * vtu, v, beta * u) : 0.0f;
        float negv = -v, negw = -w;

        // rank-2 update: r[j] -= v_row*w[j] + w_row*v[j]
        float ncol = colreg;
        #pragma unroll
        for (int j = K0 + 1; j < NDIM; ++j) {
            float vj = rl(v, j);
            float wj = rl(w, j);
            r[j] = fmaf(negv, wj, fmaf(negw, vj, r[j]));
            if (j <= K1) {
                if (j == k + 1) ncol = r[j];          // next column (static window)
            }
        }
        colreg = ncol;
        dval = (t == k + 1) ? ncol : dval;            // d[k+1] is final after iter k
    }
}

__global__ __launch_bounds__(64, 2)
void bispec_eig_kernel(const float* __restrict__ x, const float* __restrict__ y,
                       const float* __restrict__ A, const float* __restrict__ B,
                       const float* __restrict__ C, const int* __restrict__ idxp,
                       float* __restrict__ out, int batch) {
    const int b = blockIdx.x;
    const int t = threadIdx.x;
    if (b >= batch) return;

    const float xi = x[b * NDIM + t];
    const float yi = y[b * NDIM + t];

    // Symmetrized row t: r[j] = 0.5*(M[t][j] + M[j][t]),
    // M[i][j] = A[i][j] + B[i][j]*x[j] + C[i][j]*y[j].
    // x[j], y[j] broadcast from the wave's own registers via readlane.
    float r[NDIM];
    #pragma unroll
    for (int j = 0; j < NDIM; ++j) {
        float xj = rl(xi, j);
        float yj = rl(yi, j);
        float mtj = fmaf(B[t * NDIM + j], xj, fmaf(C[t * NDIM + j], yj, A[t * NDIM + j]));
        float mjt = fmaf(B[j * NDIM + t], xi, fmaf(C[j * NDIM + t], yi, A[j * NDIM + t]));
        r[j] = 0.5f * (mtj + mjt);
    }

    // ---- Householder tridiagonalization (register-only) ----
    float colreg = r[0];
    float dval = (t == 0) ? r[0] : 0.0f;
    float e2val = 0.0f;
    tri_chunk< 0, 16>(r, colreg, dval, e2val, t);
    tri_chunk<16, 32>(r, colreg, dval, e2val, t);
    tri_chunk<32, 48>(r, colreg, dval, e2val, t);
    tri_chunk<48, 62>(r, colreg, dval, e2val, t);

    // Trailing 2x2 block: d[62] captured at k=61; e[62] = A[63][62] = lane63's colreg.
    float e62 = rl(colreg, 63);
    e2val = (t == 62) ? e62 * e62 : e2val;
    dval = (t == 63) ? r[63] : dval;

    // Gershgorin bounds from tridiagonal (d, |e|)
    float eabs = sqrtf(e2val);
    float eprev = __shfl_up(eabs, 1, 64);
    eprev = (t == 0) ? 0.0f : eprev;
    float rad = eabs + eprev;
    float lo = wave_min(dval - rad);
    float hi = wave_max(dval + rad);
    float pad = 1e-3f + 1e-5f * fmaxf(fabsf(lo), fabsf(hi));
    lo -= pad;
    hi += pad;

    int idx = idxp[0];
    idx = idx < 0 ? 0 : (idx > NDIM - 1 ? NDIM - 1 : idx);

    // 64-way multisection on the Sturm sequence; d/e^2 broadcast via readlane.
    #pragma unroll 1
    for (int it = 0; it < 4; ++it) {
        float wdt = (hi - lo) * (1.0f / 65.0f);
        float s = lo + wdt * (float)(t + 1);
        float q = rl(dval, 0) - s;
        q = (fabsf(q) < 1e-12f) ? -1e-12f : q;
        int cnt = (q < 0.0f) ? 1 : 0;
        #pragma unroll
        for (int i = 1; i < NDIM; ++i) {
            float di = rl(dval, i);
            float e2i = rl(e2val, i - 1);
            q = di - s - e2i * __builtin_amdgcn_rcpf(q);
            q = (fabsf(q) < 1e-12f) ? -1e-12f : q;
            cnt += (q < 0.0f) ? 1 : 0;
        }
        unsigned long long m = __ballot(cnt <= idx);
        int p = (int)__popcll(m);
        float nlo = lo + wdt * (float)p;
        float nhi = lo + wdt * (float)(p + 1);
        lo = nlo;
        hi = (p >= 64) ? hi : nhi;
    }

    if (t == 0) out[b] = 0.5f * (lo + hi);
}

extern "C" void kernel_launch(void* const* d_in, const int* in_sizes, int n_in,
                              void* d_out, int out_size, void* d_ws, size_t ws_size,
                              hipStream_t stream) {
    const float* x = (const float*)d_in[0];
    const float* y = (const float*)d_in[1];
    const float* A = (const float*)d_in[2];
    const float* B = (const float*)d_in[3];
    const float* C = (const float*)d_in[4];
    const int* idxp = (const int*)d_in[5];
    float* out = (float*)d_out;
    int batch = in_sizes[0] / NDIM;

    dim3 grid(batch), block(NDIM);
    hipLaunchKernelGGL(bispec_eig_kernel, grid, block, 0, stream,
                       x, y, A, B, C, idxp, out, batch);
}

// Round 6
// 853.058 us; speedup vs baseline: 5.2153x; 1.1976x over previous
//
#include <hip/hip_runtime.h>
#include <math.h>

#define NDIM 64
typedef float f32x2 __attribute__((ext_vector_type(2)));

// Broadcast lane `lane`'s value to all lanes (uniform / SGPR).
__device__ __forceinline__ float rl(float v, int lane) {
    return __uint_as_float((unsigned)__builtin_amdgcn_readlane(__float_as_uint(v), lane));
}

// DPP add step: x += dpp_move(x, CTRL) with compile-time control/row mask.
template<int CTRL, int ROW_MASK>
__device__ __forceinline__ float dpp_add(float x) {
    int m = __builtin_amdgcn_update_dpp(0, __float_as_int(x), CTRL, ROW_MASK, 0xf, true);
    return x + __int_as_float(m);
}
// Full-wave64 sum via DPP (row_shr 1/2/4/8 + row_bcast 15/31), total in lane 63,
// broadcast back via readlane.
__device__ __forceinline__ float wave_sum(float x) {
    x = dpp_add<0x111, 0xf>(x);   // row_shr:1
    x = dpp_add<0x112, 0xf>(x);   // row_shr:2
    x = dpp_add<0x114, 0xf>(x);   // row_shr:4
    x = dpp_add<0x118, 0xf>(x);   // row_shr:8
    x = dpp_add<0x142, 0xa>(x);   // row_bcast:15 -> rows 1,3
    x = dpp_add<0x143, 0xc>(x);   // row_bcast:31 -> row 3
    return rl(x, 63);
}
__device__ __forceinline__ float wave_min(float v) {
    #pragma unroll
    for (int off = 1; off < 64; off <<= 1) v = fminf(v, __shfl_xor(v, off, 64));
    return v;
}
__device__ __forceinline__ float wave_max(float v) {
    #pragma unroll
    for (int off = 1; off < 64; off <<= 1) v = fmaxf(v, __shfl_xor(v, off, 64));
    return v;
}

// Householder iterations k in [K0, K1); K0 even. Columns <= K0 inert (v=w=0),
// row stored as 32 x f32x2 pairs -> v_pk_fma_f32. All cross-lane traffic via
// readlane/DPP (no LDS, no barriers).
template<int K0, int K1>
__device__ __forceinline__ void tri_chunk(f32x2 (&r2)[32], float& colreg,
                                          float& dval, float& e2val, const int t) {
    #pragma unroll 1
    for (int k = K0; k < K1; ++k) {
        float akt = (t > k) ? colreg : 0.0f;
        float s2 = wave_sum(akt * akt);
        float a1 = rl(akt, k + 1);
        float sigma = sqrtf(s2);
        float alpha = (a1 >= 0.0f) ? -sigma : sigma;     // e[k] = alpha, e[k]^2 = s2
        e2val = (t == k) ? s2 : e2val;
        float v = akt - ((t == k + 1) ? alpha : 0.0f);
        float vtv = 2.0f * (s2 - alpha * a1);            // no cancellation
        float beta = (vtv > 1e-30f) ? 2.0f * __builtin_amdgcn_rcpf(vtv) : 0.0f;

        // u = A*v over active pairs
        f32x2 acc = {0.0f, 0.0f};
        #pragma unroll
        for (int p = K0 / 2; p < 32; ++p) {
            f32x2 vv;
            vv.x = rl(v, 2 * p);
            vv.y = rl(v, 2 * p + 1);
            acc = __builtin_elementwise_fma(r2[p], vv, acc);
        }
        float u = acc.x + acc.y;
        float vtu = wave_sum(v * u);
        float w = (t > k) ? fmaf(-0.5f * beta * beta * vtu, v, beta * u) : 0.0f;
        f32x2 nv2; nv2.x = -v; nv2.y = -v;
        f32x2 nw2; nw2.x = -w; nw2.y = -w;

        // rank-2 update: r -= v*w[j] + w*v[j]
        #pragma unroll
        for (int p = K0 / 2; p < 32; ++p) {
            f32x2 vv, ww;
            vv.x = rl(v, 2 * p);     vv.y = rl(v, 2 * p + 1);
            ww.x = rl(w, 2 * p);     ww.y = rl(w, 2 * p + 1);
            r2[p] = __builtin_elementwise_fma(nv2, ww,
                    __builtin_elementwise_fma(nw2, vv, r2[p]));
        }

        // next column value (static selects within the chunk window)
        float ncol = colreg;
        #pragma unroll
        for (int j = K0 + 1; j <= K1; ++j) {
            if (j == k + 1) ncol = (j & 1) ? r2[j >> 1].y : r2[j >> 1].x;
        }
        colreg = ncol;
        dval = (t == k + 1) ? ncol : dval;               // d[k+1] final after iter k
    }
}

// One-time prep: Sa = 0.5(A+A^T), Bh = 0.5B, Bt = 0.5B^T, Ch = 0.5C, Ct = 0.5C^T.
__global__ __launch_bounds__(64)
void prep_kernel(const float* __restrict__ A, const float* __restrict__ B,
                 const float* __restrict__ C, float* __restrict__ ws) {
    const int t = threadIdx.x;
    float* Sa = ws;
    float* Bh = ws + 4096;
    float* Bt = ws + 8192;
    float* Ch = ws + 12288;
    float* Ct = ws + 16384;
    for (int j = 0; j < NDIM; ++j) {
        Sa[t * NDIM + j] = 0.5f * (A[t * NDIM + j] + A[j * NDIM + t]);
        Bh[t * NDIM + j] = 0.5f * B[t * NDIM + j];
        Bt[t * NDIM + j] = 0.5f * B[j * NDIM + t];
        Ch[t * NDIM + j] = 0.5f * C[t * NDIM + j];
        Ct[t * NDIM + j] = 0.5f * C[j * NDIM + t];
    }
}

// 256 threads = 4 independent waves = 4 matrices per block. No LDS, no barriers.
__global__ __launch_bounds__(256, 2)
void bispec_eig_kernel(const float* __restrict__ x, const float* __restrict__ y,
                       const float* __restrict__ ws, const int* __restrict__ idxp,
                       float* __restrict__ out, int batch) {
    const int t = threadIdx.x & 63;
    const int b = blockIdx.x * 4 + (threadIdx.x >> 6);
    if (b >= batch) return;

    const float xi = x[b * NDIM + t];
    const float yi = y[b * NDIM + t];

    const float4* Sa4 = (const float4*)(ws + t * NDIM);
    const float4* Bh4 = (const float4*)(ws + 4096 + t * NDIM);
    const float4* Bt4 = (const float4*)(ws + 8192 + t * NDIM);
    const float4* Ch4 = (const float4*)(ws + 12288 + t * NDIM);
    const float4* Ct4 = (const float4*)(ws + 16384 + t * NDIM);

    // r_sym[t][j] = Sa + Bh*x[j] + Bt*x[t] + Ch*y[j] + Ct*y[t]
    f32x2 r2[32];
    #pragma unroll
    for (int q = 0; q < 16; ++q) {
        float4 sa = Sa4[q], bh = Bh4[q], bt = Bt4[q], ch = Ch4[q], ct = Ct4[q];
        float e0 = fmaf(bh.x, rl(xi, 4 * q),     fmaf(bt.x, xi, fmaf(ch.x, rl(yi, 4 * q),     fmaf(ct.x, yi, sa.x))));
        float e1 = fmaf(bh.y, rl(xi, 4 * q + 1), fmaf(bt.y, xi, fmaf(ch.y, rl(yi, 4 * q + 1), fmaf(ct.y, yi, sa.y))));
        float e2 = fmaf(bh.z, rl(xi, 4 * q + 2), fmaf(bt.z, xi, fmaf(ch.z, rl(yi, 4 * q + 2), fmaf(ct.z, yi, sa.z))));
        float e3 = fmaf(bh.w, rl(xi, 4 * q + 3), fmaf(bt.w, xi, fmaf(ch.w, rl(yi, 4 * q + 3), fmaf(ct.w, yi, sa.w))));
        r2[2 * q].x = e0;     r2[2 * q].y = e1;
        r2[2 * q + 1].x = e2; r2[2 * q + 1].y = e3;
    }

    // ---- Householder tridiagonalization (register-only, packed) ----
    float colreg = r2[0].x;
    float dval = (t == 0) ? r2[0].x : 0.0f;
    float e2val = 0.0f;
    tri_chunk< 0,  8>(r2, colreg, dval, e2val, t);
    tri_chunk< 8, 16>(r2, colreg, dval, e2val, t);
    tri_chunk<16, 24>(r2, colreg, dval, e2val, t);
    tri_chunk<24, 32>(r2, colreg, dval, e2val, t);
    tri_chunk<32, 40>(r2, colreg, dval, e2val, t);
    tri_chunk<40, 48>(r2, colreg, dval, e2val, t);
    tri_chunk<48, 56>(r2, colreg, dval, e2val, t);
    tri_chunk<56, 62>(r2, colreg, dval, e2val, t);

    // Trailing 2x2: e[62] = lane63's colreg; d[63] = r[63].
    float e62 = rl(colreg, 63);
    e2val = (t == 62) ? e62 * e62 : e2val;
    dval = (t == 63) ? r2[31].y : dval;

    // Gershgorin bounds
    float eabs = sqrtf(e2val);
    float eprev = __shfl_up(eabs, 1, 64);
    eprev = (t == 0) ? 0.0f : eprev;
    float rad = eabs + eprev;
    float lo = wave_min(dval - rad);
    float hi = wave_max(dval + rad);
    float pad = 1e-3f + 1e-5f * fmaxf(fabsf(lo), fabsf(hi));
    lo -= pad;
    hi += pad;

    int idx = idxp[0];
    idx = idx < 0 ? 0 : (idx > NDIM - 1 ? NDIM - 1 : idx);

    // 64-way multisection on the Sturm sequence (3 iters -> ~5e-5 width)
    #pragma unroll 1
    for (int it = 0; it < 3; ++it) {
        float wdt = (hi - lo) * (1.0f / 65.0f);
        float s = lo + wdt * (float)(t + 1);
        float q = rl(dval, 0) - s;
        q = (fabsf(q) < 1e-12f) ? -1e-12f : q;
        int cnt = (q < 0.0f) ? 1 : 0;
        #pragma unroll
        for (int i = 1; i < NDIM; ++i) {
            q = rl(dval, i) - s - rl(e2val, i - 1) * __builtin_amdgcn_rcpf(q);
            q = (fabsf(q) < 1e-12f) ? -1e-12f : q;
            cnt += (q < 0.0f) ? 1 : 0;
        }
        unsigned long long m = __ballot(cnt <= idx);
        int p = (int)__popcll(m);
        float nlo = lo + wdt * (float)p;
        float nhi = lo + wdt * (float)(p + 1);
        lo = nlo;
        hi = (p >= 64) ? hi : nhi;
    }

    if (t == 0) out[b] = 0.5f * (lo + hi);
}

extern "C" void kernel_launch(void* const* d_in, const int* in_sizes, int n_in,
                              void* d_out, int out_size, void* d_ws, size_t ws_size,
                              hipStream_t stream) {
    const float* x = (const float*)d_in[0];
    const float* y = (const float*)d_in[1];
    const float* A = (const float*)d_in[2];
    const float* B = (const float*)d_in[3];
    const float* C = (const float*)d_in[4];
    const int* idxp = (const int*)d_in[5];
    float* out = (float*)d_out;
    float* ws = (float*)d_ws;
    int batch = in_sizes[0] / NDIM;

    hipLaunchKernelGGL(prep_kernel, dim3(1), dim3(64), 0, stream, A, B, C, ws);
    hipLaunchKernelGGL(bispec_eig_kernel, dim3((batch + 3) / 4), dim3(256), 0, stream,
                       x, y, ws, idxp, out, batch);
}

// Round 8
// 833.395 us; speedup vs baseline: 5.3384x; 1.0236x over previous
//
#include <hip/hip_runtime.h>
#include <math.h>

#define NDIM 64
typedef float f32x2 __attribute__((ext_vector_type(2)));

#define MEMFENCE() asm volatile("" ::: "memory")

// Broadcast lane `lane`'s value to all lanes (uniform / SGPR).
__device__ __forceinline__ float rl(float v, int lane) {
    return __uint_as_float((unsigned)__builtin_amdgcn_readlane(__float_as_uint(v), lane));
}

// DPP add step with compile-time control/row mask.
template<int CTRL, int ROW_MASK>
__device__ __forceinline__ float dpp_add(float x) {
    int m = __builtin_amdgcn_update_dpp(0, __float_as_int(x), CTRL, ROW_MASK, 0xf, true);
    return x + __int_as_float(m);
}
// Full-wave64 sum via DPP; total lands in lane 63, broadcast via readlane.
__device__ __forceinline__ float wave_sum(float x) {
    x = dpp_add<0x111, 0xf>(x);   // row_shr:1
    x = dpp_add<0x112, 0xf>(x);   // row_shr:2
    x = dpp_add<0x114, 0xf>(x);   // row_shr:4
    x = dpp_add<0x118, 0xf>(x);   // row_shr:8
    x = dpp_add<0x142, 0xa>(x);   // row_bcast:15 -> rows 1,3
    x = dpp_add<0x143, 0xc>(x);   // row_bcast:31 -> row 3
    return rl(x, 63);
}
__device__ __forceinline__ float wave_min(float v) {
    #pragma unroll
    for (int off = 1; off < 64; off <<= 1) v = fminf(v, __shfl_xor(v, off, 64));
    return v;
}
__device__ __forceinline__ float wave_max(float v) {
    #pragma unroll
    for (int off = 1; off < 64; off <<= 1) v = fmaxf(v, __shfl_xor(v, off, 64));
    return v;
}

// Householder iterations k in [K0, K1); K0 multiple of 8. Columns <= K0 are
// inert (v=w=0). Row held as 32 x f32x2 (v_pk_fma_f32). v/w broadcast through
// per-wave LDS buffers read as float4 (same-address broadcast, conflict-free).
// Intra-wave ds_write -> ds_read is HW-ordered; MEMFENCE() pins compiler order.
template<int K0, int K1>
__device__ __forceinline__ void tri_chunk(f32x2 (&r2)[32], float& colreg,
                                          float& dval, float& e2val, const int t,
                                          float4* vb4, float4* wb4) {
    float* vbp = (float*)vb4;
    float* wbp = (float*)wb4;
    constexpr int Q0 = K0 / 4;          // first active float4 (4 elements each)
    #pragma unroll 1
    for (int k = K0; k < K1; ++k) {
        float akt = (t > k) ? colreg : 0.0f;
        float s2 = wave_sum(akt * akt);
        float a1 = rl(akt, k + 1);
        float sigma = sqrtf(s2);
        float alpha = (a1 >= 0.0f) ? -sigma : sigma;   // e[k] = alpha, e[k]^2 = s2
        e2val = (t == k) ? s2 : e2val;
        float v = akt - ((t == k + 1) ? alpha : 0.0f);
        float vtv = 2.0f * (s2 - alpha * a1);          // no cancellation
        float beta = (vtv > 1e-30f) ? 2.0f * __builtin_amdgcn_rcpf(vtv) : 0.0f;
        vbp[t] = v;
        MEMFENCE();

        // u = A*v, streaming v from LDS as float4 broadcasts
        f32x2 acc = {0.0f, 0.0f};
        #pragma unroll
        for (int q = Q0; q < 16; ++q) {
            float4 vq = vb4[q];
            f32x2 v01; v01.x = vq.x; v01.y = vq.y;
            f32x2 v23; v23.x = vq.z; v23.y = vq.w;
            acc = __builtin_elementwise_fma(r2[2 * q],     v01, acc);
            acc = __builtin_elementwise_fma(r2[2 * q + 1], v23, acc);
        }
        float u = acc.x + acc.y;
        float vtu = wave_sum(v * u);
        float w = (t > k) ? fmaf(-0.5f * beta * beta * vtu, v, beta * u) : 0.0f;
        wbp[t] = w;
        MEMFENCE();
        f32x2 nv2; nv2.x = -v; nv2.y = -v;
        f32x2 nw2; nw2.x = -w; nw2.y = -w;

        // rank-2 update: r -= v*w[j] + w*v[j]
        #pragma unroll
        for (int q = Q0; q < 16; ++q) {
            float4 vq = vb4[q];
            float4 wq = wb4[q];
            f32x2 v01; v01.x = vq.x; v01.y = vq.y;
            f32x2 v23; v23.x = vq.z; v23.y = vq.w;
            f32x2 w01; w01.x = wq.x; w01.y = wq.y;
            f32x2 w23; w23.x = wq.z; w23.y = wq.w;
            r2[2 * q]     = __builtin_elementwise_fma(nv2, w01,
                            __builtin_elementwise_fma(nw2, v01, r2[2 * q]));
            r2[2 * q + 1] = __builtin_elementwise_fma(nv2, w23,
                            __builtin_elementwise_fma(nw2, v23, r2[2 * q + 1]));
        }

        // next column value (static selects within the chunk window)
        float ncol = colreg;
        #pragma unroll
        for (int j = K0 + 1; j <= K1; ++j) {
            if (j == k + 1) ncol = (j & 1) ? r2[j >> 1].y : r2[j >> 1].x;
        }
        colreg = ncol;
        dval = (t == k + 1) ? ncol : dval;             // d[k+1] final after iter k
    }
}

// One-time prep: Sa = 0.5(A+A^T), Bh = 0.5B, Bt = 0.5B^T, Ch = 0.5C, Ct = 0.5C^T.
__global__ __launch_bounds__(64)
void prep_kernel(const float* __restrict__ A, const float* __restrict__ B,
                 const float* __restrict__ C, float* __restrict__ ws) {
    const int t = threadIdx.x;
    float* Sa = ws;
    float* Bh = ws + 4096;
    float* Bt = ws + 8192;
    float* Ch = ws + 12288;
    float* Ct = ws + 16384;
    for (int j = 0; j < NDIM; ++j) {
        Sa[t * NDIM + j] = 0.5f * (A[t * NDIM + j] + A[j * NDIM + t]);
        Bh[t * NDIM + j] = 0.5f * B[t * NDIM + j];
        Bt[t * NDIM + j] = 0.5f * B[j * NDIM + t];
        Ch[t * NDIM + j] = 0.5f * C[t * NDIM + j];
        Ct[t * NDIM + j] = 0.5f * C[j * NDIM + t];
    }
}

// 256 threads = 4 independent waves = 4 matrices per block. Per-wave private
// LDS slices; no barriers.
__global__ __launch_bounds__(256, 2)
void bispec_eig_kernel(const float* __restrict__ x, const float* __restrict__ y,
                       const float* __restrict__ ws, const int* __restrict__ idxp,
                       float* __restrict__ out, int batch) {
    const int t = threadIdx.x & 63;
    const int wv = threadIdx.x >> 6;
    const int b = blockIdx.x * 4 + wv;
    if (b >= batch) return;

    __shared__ float4 vb4s[4][16];
    __shared__ float4 wb4s[4][16];
    __shared__ float2 des[4][64];
    float4* vb4 = vb4s[wv];
    float4* wb4 = wb4s[wv];
    float2* dep = des[wv];

    const float xi = x[b * NDIM + t];
    const float yi = y[b * NDIM + t];
    ((float*)vb4)[t] = xi;            // x broadcast (buffer reused for v later)
    ((float*)wb4)[t] = yi;            // y broadcast (buffer reused for w later)
    MEMFENCE();

    const float4* Sa4 = (const float4*)(ws + t * NDIM);
    const float4* Bh4 = (const float4*)(ws + 4096 + t * NDIM);
    const float4* Bt4 = (const float4*)(ws + 8192 + t * NDIM);
    const float4* Ch4 = (const float4*)(ws + 12288 + t * NDIM);
    const float4* Ct4 = (const float4*)(ws + 16384 + t * NDIM);

    // r_sym[t][j] = Sa + Bh*x[j] + Bt*x[t] + Ch*y[j] + Ct*y[t]
    f32x2 r2[32];
    #pragma unroll
    for (int q = 0; q < 16; ++q) {
        float4 sa = Sa4[q], bh = Bh4[q], bt = Bt4[q], ch = Ch4[q], ct = Ct4[q];
        float4 xq = vb4[q], yq = wb4[q];
        float e0 = fmaf(bh.x, xq.x, fmaf(bt.x, xi, fmaf(ch.x, yq.x, fmaf(ct.x, yi, sa.x))));
        float e1 = fmaf(bh.y, xq.y, fmaf(bt.y, xi, fmaf(ch.y, yq.y, fmaf(ct.y, yi, sa.y))));
        float e2 = fmaf(bh.z, xq.z, fmaf(bt.z, xi, fmaf(ch.z, yq.z, fmaf(ct.z, yi, sa.z))));
        float e3 = fmaf(bh.w, xq.w, fmaf(bt.w, xi, fmaf(ch.w, yq.w, fmaf(ct.w, yi, sa.w))));
        r2[2 * q].x = e0;     r2[2 * q].y = e1;
        r2[2 * q + 1].x = e2; r2[2 * q + 1].y = e3;
    }

    // ---- Householder tridiagonalization ----
    float colreg = r2[0].x;
    float dval = (t == 0) ? r2[0].x : 0.0f;
    float e2val = 0.0f;
    tri_chunk< 0,  8>(r2, colreg, dval, e2val, t, vb4, wb4);
    tri_chunk< 8, 16>(r2, colreg, dval, e2val, t, vb4, wb4);
    tri_chunk<16, 24>(r2, colreg, dval, e2val, t, vb4, wb4);
    tri_chunk<24, 32>(r2, colreg, dval, e2val, t, vb4, wb4);
    tri_chunk<32, 40>(r2, colreg, dval, e2val, t, vb4, wb4);
    tri_chunk<40, 48>(r2, colreg, dval, e2val, t, vb4, wb4);
    tri_chunk<48, 56>(r2, colreg, dval, e2val, t, vb4, wb4);
    tri_chunk<56, 62>(r2, colreg, dval, e2val, t, vb4, wb4);

    // Trailing 2x2: e[62] = lane63's colreg; d[63] = r[63].
    float e62 = rl(colreg, 63);
    e2val = (t == 62) ? e62 * e62 : e2val;
    dval = (t == 63) ? r2[31].y : dval;

    // Stash (d_t, e^2_{t-1}) pairs for the Sturm phase.
    float e2prev = __shfl_up(e2val, 1, 64);
    e2prev = (t == 0) ? 0.0f : e2prev;
    float2 dp; dp.x = dval; dp.y = e2prev;
    dep[t] = dp;
    MEMFENCE();

    // Gershgorin bounds
    float eabs = sqrtf(e2val);
    float eprev = __shfl_up(eabs, 1, 64);
    eprev = (t == 0) ? 0.0f : eprev;
    float rad = eabs + eprev;
    float lo = wave_min(dval - rad);
    float hi = wave_max(dval + rad);
    float pad = 1e-3f + 1e-5f * fmaxf(fabsf(lo), fabsf(hi));
    lo -= pad;
    hi += pad;

    int idx = idxp[0];
    idx = idx < 0 ? 0 : (idx > NDIM - 1 ? NDIM - 1 : idx);

    // 64-way multisection on the Sturm sequence (3 iters)
    #pragma unroll 1
    for (int it = 0; it < 3; ++it) {
        float wdt = (hi - lo) * (1.0f / 65.0f);
        float s = lo + wdt * (float)(t + 1);
        float2 p0 = dep[0];
        float q = p0.x - s;
        q = (fabsf(q) < 1e-12f) ? -1e-12f : q;
        int cnt = (q < 0.0f) ? 1 : 0;
        #pragma unroll
        for (int i = 1; i < NDIM; ++i) {
            float2 pi = dep[i];
            q = pi.x - s - pi.y * __builtin_amdgcn_rcpf(q);
            q = (fabsf(q) < 1e-12f) ? -1e-12f : q;
            cnt += (q < 0.0f) ? 1 : 0;
        }
        unsigned long long m = __ballot(cnt <= idx);
        int p = (int)__popcll(m);
        float nlo = lo + wdt * (float)p;
        float nhi = lo + wdt * (float)(p + 1);
        lo = nlo;
        hi = (p >= 64) ? hi : nhi;
    }

    if (t == 0) out[b] = 0.5f * (lo + hi);
}

extern "C" void kernel_launch(void* const* d_in, const int* in_sizes, int n_in,
                              void* d_out, int out_size, void* d_ws, size_t ws_size,
                              hipStream_t stream) {
    const float* x = (const float*)d_in[0];
    const float* y = (const float*)d_in[1];
    const float* A = (const float*)d_in[2];
    const float* B = (const float*)d_in[3];
    const float* C = (const float*)d_in[4];
    const int* idxp = (const int*)d_in[5];
    float* out = (float*)d_out;
    float* ws = (float*)d_ws;
    int batch = in_sizes[0] / NDIM;

    hipLaunchKernelGGL(prep_kernel, dim3(1), dim3(64), 0, stream, A, B, C, ws);
    hipLaunchKernelGGL(bispec_eig_kernel, dim3((batch + 3) / 4), dim3(256), 0, stream,
                       x, y, ws, idxp, out, batch);
}